// Round 5
// baseline (152.042 us; speedup 1.0000x reference)
//
#include <hip/hip_runtime.h>
#include <hip/hip_bf16.h>

// Problem constants: E=4 edge types, B=262144 tokens, C=128 dim
#define N_E 4
#define N_B 262144
#define N_C 128

typedef __attribute__((ext_vector_type(8))) short bf16x8;   // MFMA A/B frag (8 bf16)
typedef __attribute__((ext_vector_type(4))) float f32x4;    // MFMA C/D frag
typedef __attribute__((ext_vector_type(4))) unsigned int u32x4;

// pack two fp32 -> u32 of 2 bf16 (RNE) via v_cvt_pk_bf16_f32
__device__ __forceinline__ unsigned pk2(float lo, float hi) {
  float2 t; t.x = lo; t.y = hi;
  __hip_bfloat162 h = __float22bfloat162_rn(t);
  union { __hip_bfloat162 h; unsigned u; } c;
  c.h = h;
  return c.u;
}

// out[b][d] = sum_e sum_c xs[e][b][c]*Ws[e][c][d] + sum_e bs[e][d]
// M=262144, N=128, K=512; memory-bound.
//
// vs R4 (145.9us): (1) ONE persistent 16-wave block per CU (grid=256); each wave
// runs 4 row-tiles = 64 pipelined steps, pipeline FLOWS across tile boundaries
// (no drain, W staged once, one ramp). (2) swapped-operand MFMA (A=W, B=x) makes
// the C/D layout d-major per lane -> epilogue is 8x global_store_dwordx4 (16B/lane)
// instead of 32 scalar stores. Stores enter vmcnt, so the wait table accounts for
// them: tile t>0 steps 0-3 wait vmcnt(14) (queue = 8 loads + 8 stores; retire the
// 2 oldest loads only), step 4 wait(6) retires the aged stores. Hand-simulated
// for all 64 steps. sched_barrier(0) after every wait (rule #18).
__global__ void __launch_bounds__(1024, 4)
grouped_gemm(const float* __restrict__ xs, const float* __restrict__ Ws,
             const float* __restrict__ bs, float* __restrict__ out) {
  extern __shared__ unsigned char smem[];
  unsigned short* lds_w   = (unsigned short*)smem;   // 8192 entries * 16B = 128 KiB
  float*          lds_bias = (float*)(smem + 131072); // 512 B

  const int tid  = threadIdx.x;
  const int lane = tid & 63;
  const int wave = tid >> 6;       // 0..15
  const int l15  = lane & 15;
  const int hi   = lane >> 4;
  const int rowBase = blockIdx.x * 1024 + wave * 16;  // + rt*256 per row-tile

  // ---- stage ALL W (4x128x128 fp32) -> LDS bf16 fragment layout (once) ----
  // entry m: e=m>>11, u=(m>>7)&15, d=m&127 ; holds Ws[e][u*8+j][d], j=0..7 (16B)
#pragma unroll
  for (int i = 0; i < 8; ++i) {
    int m = tid + i * 1024;
    int e = m >> 11;
    int u = (m >> 7) & 15;
    int d = m & 127;
    const float* src = Ws + e * (N_C * N_C) + u * 8 * N_C + d;
    float v[8];
#pragma unroll
    for (int j = 0; j < 8; ++j) v[j] = src[j * N_C];
    u32x4 pk;
#pragma unroll
    for (int j = 0; j < 4; ++j) pk[j] = pk2(v[2 * j], v[2 * j + 1]);
    *reinterpret_cast<u32x4*>(&lds_w[(size_t)m * 8]) = pk;
  }
  if (tid < 128) {
    lds_bias[tid] = bs[tid] + bs[128 + tid] + bs[256 + tid] + bs[384 + tid];
  }
  // Drain ALL compiler-emitted vmem so loop vmcnt counts are exact.
  asm volatile("s_waitcnt vmcnt(0)" ::: "memory");
  __syncthreads();  // the only barrier

  // ---- A stream: 64 chunks t: rt=t>>4, e=(t>>2)&3, kt=t&3 ----
  // lane reads 32B of row rowBase + rt*256 + l15, bytes kt*128 + hi*32
  const unsigned vb = (unsigned)(rowBase + l15) * 512u + (unsigned)hi * 32u;
  const unsigned long long xbase = (unsigned long long)xs;

  f32x4 A0[4], A1[4];  // 4-deep rotating chunk buffer (statically indexed only)

#define AISSUE(c)                                                              \
  do {                                                                         \
    unsigned o;                                                                \
    asm volatile("v_add_u32 %0, %1, %2"                                        \
                 : "=v"(o)                                                     \
                 : "n"((((c) >> 4) * 131072u) + ((((c) >> 2) & 3) * 134217728u) \
                       + (((c) & 3) * 128u)),                                  \
                   "v"(vb));                                                   \
    asm volatile("global_load_dwordx4 %0, %2, %3 offset:0\n\t"                 \
                 "global_load_dwordx4 %1, %2, %3 offset:16"                    \
                 : "=&v"(A0[(c) & 3]), "=&v"(A1[(c) & 3])                      \
                 : "v"(o), "s"(xbase)                                          \
                 : "memory");                                                  \
  } while (0)

#define WAITV(n)                                          \
  do {                                                    \
    asm volatile("s_waitcnt vmcnt(" #n ")" ::: "memory"); \
    __builtin_amdgcn_sched_barrier(0);                    \
  } while (0)

  f32x4 acc[8];
#pragma unroll
  for (int n = 0; n < 8; ++n) {
    f32x4 z = {0.0f, 0.0f, 0.0f, 0.0f};
    acc[n] = z;
  }

  AISSUE(0); AISSUE(1); AISSUE(2); AISSUE(3);

  // STEP(t,w): wait chunk t (vmcnt(w)), build x-frag, refill chunk t+4,
  // 8x mfma(Wfrag, xfrag, acc). Swapped operands: D row=(hi*4+r)=d, col=l15=token.
#define STEP(t, w)                                                             \
  do {                                                                         \
    WAITV(w);                                                                  \
    f32x4 a0 = A0[(t) & 3];                                                    \
    f32x4 a1 = A1[(t) & 3];                                                    \
    bf16x8 xfrag;                                                              \
    unsigned* au = reinterpret_cast<unsigned*>(&xfrag);                        \
    au[0] = pk2(a0[0], a0[1]);                                                 \
    au[1] = pk2(a0[2], a0[3]);                                                 \
    au[2] = pk2(a1[0], a1[1]);                                                 \
    au[3] = pk2(a1[2], a1[3]);                                                 \
    if ((t) <= 59) AISSUE((t) + 4);                                            \
    const unsigned short* wb =                                                 \
        lds_w + (size_t)(((((t) >> 2) & 3) * 16 + ((t) & 3) * 4 + hi) * 128 + l15) * 8; \
    _Pragma("unroll")                                                          \
    for (int n = 0; n < 8; ++n) {                                              \
      bf16x8 wfrag = *reinterpret_cast<const bf16x8*>(wb + (size_t)n * 128);   \
      acc[n] = __builtin_amdgcn_mfma_f32_16x16x32_bf16(wfrag, xfrag, acc[n], 0, 0, 0); \
    }                                                                          \
  } while (0)

  // EPILOGUE(rt): lane (l15,hi) holds out[row=rowBase+rt*256+l15][d=n*16+hi*4+r],
  // r=0..3 -> one dwordx4 per n. Bias from LDS (lgkm only; vmcnt untouched).
#define EPILOGUE(rt)                                                           \
  do {                                                                         \
    float* ob = out + (size_t)(rowBase + (rt) * 256 + l15) * N_C + hi * 4;     \
    _Pragma("unroll")                                                          \
    for (int n = 0; n < 8; ++n) {                                              \
      f32x4 bv = *reinterpret_cast<const f32x4*>(&lds_bias[n * 16 + hi * 4]);  \
      f32x4 v = acc[n] + bv;                                                   \
      *reinterpret_cast<f32x4*>(ob + n * 16) = v;                              \
      f32x4 z = {0.0f, 0.0f, 0.0f, 0.0f};                                      \
      acc[n] = z;                                                              \
    }                                                                          \
  } while (0)

  // tile 0: queue holds 8 loads throughout -> wait(6)
  STEP(0, 6);  STEP(1, 6);  STEP(2, 6);  STEP(3, 6);
  STEP(4, 6);  STEP(5, 6);  STEP(6, 6);  STEP(7, 6);
  STEP(8, 6);  STEP(9, 6);  STEP(10, 6); STEP(11, 6);
  STEP(12, 6); STEP(13, 6); STEP(14, 6); STEP(15, 6);
  EPILOGUE(0);  // 8 stores enter vmcnt AFTER chunk-19 refill
  // tile 1: steps 0-3 queue = [8 loads, 8 stores] -> wait(14); step 4 retires stores
  STEP(16, 14); STEP(17, 14); STEP(18, 14); STEP(19, 14);
  STEP(20, 6);  STEP(21, 6);  STEP(22, 6);  STEP(23, 6);
  STEP(24, 6);  STEP(25, 6);  STEP(26, 6);  STEP(27, 6);
  STEP(28, 6);  STEP(29, 6);  STEP(30, 6);  STEP(31, 6);
  EPILOGUE(1);
  STEP(32, 14); STEP(33, 14); STEP(34, 14); STEP(35, 14);
  STEP(36, 6);  STEP(37, 6);  STEP(38, 6);  STEP(39, 6);
  STEP(40, 6);  STEP(41, 6);  STEP(42, 6);  STEP(43, 6);
  STEP(44, 6);  STEP(45, 6);  STEP(46, 6);  STEP(47, 6);
  EPILOGUE(2);
  // tile 3: no next tile -> queue shrinks over the last 4 steps
  STEP(48, 14); STEP(49, 14); STEP(50, 14); STEP(51, 14);
  STEP(52, 6);  STEP(53, 6);  STEP(54, 6);  STEP(55, 6);
  STEP(56, 6);  STEP(57, 6);  STEP(58, 6);  STEP(59, 6);
  STEP(60, 6);  STEP(61, 4);  STEP(62, 2);  STEP(63, 0);
  EPILOGUE(3);

#undef STEP
#undef EPILOGUE
#undef WAITV
#undef AISSUE
}

extern "C" void kernel_launch(void* const* d_in, const int* in_sizes, int n_in,
                              void* d_out, int out_size, void* d_ws, size_t ws_size,
                              hipStream_t stream) {
  const float* xs = (const float*)d_in[0];  // [4][262144][128] fp32
  const float* Ws = (const float*)d_in[1];  // [4][128][128] fp32
  const float* bs = (const float*)d_in[2];  // [4][128] fp32
  float* out = (float*)d_out;               // [262144][128] fp32

  const size_t smem = 131072 + 512;  // W frag layout + bias
  hipFuncSetAttribute((const void*)grouped_gemm,
                      hipFuncAttributeMaxDynamicSharedMemorySize, (int)smem);

  dim3 grid(N_B / 1024);  // 256 blocks: one persistent block per CU
  dim3 block(1024);       // 16 waves/CU
  hipLaunchKernelGGL(grouped_gemm, grid, block, smem, stream, xs, Ws, bs, out);
}

// Round 6
// 147.257 us; speedup vs baseline: 1.0325x; 1.0325x over previous
//
#include <hip/hip_runtime.h>
#include <hip/hip_bf16.h>

// Problem constants: E=4 edge types, B=262144 tokens, C=128 dim
#define N_E 4
#define N_B 262144
#define N_C 128

typedef __attribute__((ext_vector_type(8))) short bf16x8;   // MFMA A/B frag (8 bf16)
typedef __attribute__((ext_vector_type(4))) float f32x4;    // MFMA C/D frag
typedef __attribute__((ext_vector_type(4))) unsigned int u32x4;

// pack two fp32 -> u32 of 2 bf16 (RNE) via v_cvt_pk_bf16_f32
__device__ __forceinline__ unsigned pk2(float lo, float hi) {
  float2 t; t.x = lo; t.y = hi;
  __hip_bfloat162 h = __float22bfloat162_rn(t);
  union { __hip_bfloat162 h; unsigned u; } c;
  c.h = h;
  return c.u;
}

// out[b][d] = sum_e sum_c xs[e][b][c]*Ws[e][c][d] + sum_e bs[e][d]
// M=262144, N=128, K=512; memory-bound.
//
// Base = R4 (145.9us best). Single change this round: NON-TEMPORAL hints on the
// zero-reuse streams. xs (537MB, read once) loads get the `nt` flag -> no
// allocate/evict churn through L2 + 256MB Infinity Cache; out (134MB, written
// once) uses __builtin_nontemporal_store. Hypothesis: streaming reads allocating
// in two cache levels are what pins read BW at ~4.6 TB/s while pure writes hit
// 6.8 TB/s on this device.
//
// Pipeline (unchanged): 16 waves/CU, per-wave 4-deep rotating register buffer,
// hand-counted s_waitcnt vmcnt(6/4/2/0) (the only vmem in the loop is ours),
// sched_barrier(0) after every wait (rule #18), no barriers in the loop.
// W (all 4 e) in LDS bf16 fragment layout (128 KiB), staged once.
__global__ void __launch_bounds__(1024, 4)
grouped_gemm(const float* __restrict__ xs, const float* __restrict__ Ws,
             const float* __restrict__ bs, float* __restrict__ out) {
  extern __shared__ unsigned char smem[];
  unsigned short* lds_w = (unsigned short*)smem;  // 8192 entries * 16B = 128 KiB

  const int tid  = threadIdx.x;
  const int lane = tid & 63;
  const int wave = tid >> 6;       // 0..15
  const int l15  = lane & 15;
  const int hi   = lane >> 4;
  const int waveRow = blockIdx.x * 256 + wave * 16;

  // ---- bias -> registers ----
  float bias[8];
#pragma unroll
  for (int n = 0; n < 8; ++n) {
    int d = n * 16 + l15;
    bias[n] = bs[d] + bs[128 + d] + bs[256 + d] + bs[384 + d];
  }

  // ---- stage ALL W (4x128x128 fp32) -> LDS bf16 fragment layout (once) ----
  // entry m: e=m>>11, u=(m>>7)&15, d=m&127 ; holds Ws[e][u*8+j][d], j=0..7 (16B)
#pragma unroll
  for (int i = 0; i < 8; ++i) {
    int m = tid + i * 1024;
    int e = m >> 11;
    int u = (m >> 7) & 15;
    int d = m & 127;
    const float* src = Ws + e * (N_C * N_C) + u * 8 * N_C + d;
    float v[8];
#pragma unroll
    for (int j = 0; j < 8; ++j) v[j] = src[j * N_C];
    u32x4 pk;
#pragma unroll
    for (int j = 0; j < 4; ++j) pk[j] = pk2(v[2 * j], v[2 * j + 1]);
    *reinterpret_cast<u32x4*>(&lds_w[(size_t)m * 8]) = pk;
  }

  // Drain ALL compiler-emitted vmem (bias + W gather) so loop vmcnt counts are exact.
  asm volatile("s_waitcnt vmcnt(0)" ::: "memory");
  __syncthreads();  // the only barrier

  // ---- A stream: 16 chunks (e=s>>2, kt=s&3); lane reads 32B of row waveRow+l15 ----
  const unsigned vb = (unsigned)(waveRow + l15) * 512u + (unsigned)hi * 32u;
  const unsigned long long xbase = (unsigned long long)xs;

  f32x4 A0[4], A1[4];  // 4-deep rotating chunk buffer (statically indexed only)

#define AISSUE(c)                                                              \
  do {                                                                         \
    unsigned o;                                                                \
    asm volatile("v_add_u32 %0, %1, %2"                                        \
                 : "=v"(o)                                                     \
                 : "n"(((c) >> 2) * 134217728u + ((c) & 3) * 128u), "v"(vb));  \
    asm volatile("global_load_dwordx4 %0, %2, %3 offset:0 nt\n\t"              \
                 "global_load_dwordx4 %1, %2, %3 offset:16 nt"                 \
                 : "=&v"(A0[(c) & 3]), "=&v"(A1[(c) & 3])                      \
                 : "v"(o), "s"(xbase)                                          \
                 : "memory");                                                  \
  } while (0)

#define WAITV(n)                                          \
  do {                                                    \
    asm volatile("s_waitcnt vmcnt(" #n ")" ::: "memory"); \
    __builtin_amdgcn_sched_barrier(0);                    \
  } while (0)

  f32x4 acc[8];
#pragma unroll
  for (int n = 0; n < 8; ++n) {
    f32x4 z = {0.0f, 0.0f, 0.0f, 0.0f};
    acc[n] = z;
  }

  AISSUE(0); AISSUE(1); AISSUE(2); AISSUE(3);

  // STEP(s): wait chunk s, convert, refill slot, 8 x MFMA against LDS-resident W
#define STEP(s, w)                                                             \
  do {                                                                         \
    WAITV(w);                                                                  \
    f32x4 a0 = A0[(s) & 3];                                                    \
    f32x4 a1 = A1[(s) & 3];                                                    \
    bf16x8 afrag;                                                              \
    unsigned* au = reinterpret_cast<unsigned*>(&afrag);                        \
    au[0] = pk2(a0[0], a0[1]);                                                 \
    au[1] = pk2(a0[2], a0[3]);                                                 \
    au[2] = pk2(a1[0], a1[1]);                                                 \
    au[3] = pk2(a1[2], a1[3]);                                                 \
    if ((s) <= 11) AISSUE((s) + 4);                                            \
    const unsigned short* wb =                                                 \
        lds_w + (size_t)((((s) >> 2) * 16 + ((s) & 3) * 4 + hi) * 128 + l15) * 8; \
    _Pragma("unroll")                                                          \
    for (int n = 0; n < 8; ++n) {                                              \
      bf16x8 bfrag = *reinterpret_cast<const bf16x8*>(wb + (size_t)n * 128);   \
      acc[n] = __builtin_amdgcn_mfma_f32_16x16x32_bf16(afrag, bfrag, acc[n], 0, 0, 0); \
    }                                                                          \
  } while (0)

  STEP(0, 6);  STEP(1, 6);  STEP(2, 6);  STEP(3, 6);
  STEP(4, 6);  STEP(5, 6);  STEP(6, 6);  STEP(7, 6);
  STEP(8, 6);  STEP(9, 6);  STEP(10, 6); STEP(11, 6);
  STEP(12, 6); STEP(13, 4); STEP(14, 2); STEP(15, 0);

#undef STEP
#undef WAITV
#undef AISSUE

  // ---- epilogue: + bias, nontemporal stores. C/D: col=lane&15, row=(lane>>4)*4+reg ----
#pragma unroll
  for (int n = 0; n < 8; ++n) {
    int d = n * 16 + l15;
#pragma unroll
    for (int r = 0; r < 4; ++r) {
      int row = waveRow + hi * 4 + r;
      __builtin_nontemporal_store(acc[n][r] + bias[n], &out[(size_t)row * N_C + d]);
    }
  }
}

extern "C" void kernel_launch(void* const* d_in, const int* in_sizes, int n_in,
                              void* d_out, int out_size, void* d_ws, size_t ws_size,
                              hipStream_t stream) {
  const float* xs = (const float*)d_in[0];  // [4][262144][128] fp32
  const float* Ws = (const float*)d_in[1];  // [4][128][128] fp32
  const float* bs = (const float*)d_in[2];  // [4][128] fp32
  float* out = (float*)d_out;               // [262144][128] fp32

  const size_t smem = 131072;  // W bf16 frag layout, all 4 edge types
  hipFuncSetAttribute((const void*)grouped_gemm,
                      hipFuncAttributeMaxDynamicSharedMemorySize, (int)smem);

  dim3 grid(N_B / 256);   // 1024 blocks (256 rows each), 4 generations/CU
  dim3 block(1024);       // 16 waves -> 16 waves/CU (VGPR capped at 128)
  hipLaunchKernelGGL(grouped_gemm, grid, block, smem, stream, xs, Ws, bs, out);
}

// Round 7
// 146.223 us; speedup vs baseline: 1.0398x; 1.0071x over previous
//
#include <hip/hip_runtime.h>
#include <hip/hip_bf16.h>

// Problem constants: E=4 edge types, B=262144 tokens, C=128 dim
#define N_E 4
#define N_B 262144
#define N_C 128

typedef __attribute__((ext_vector_type(8))) short bf16x8;   // MFMA A/B frag (8 bf16)
typedef __attribute__((ext_vector_type(4))) float f32x4;    // MFMA C/D frag
typedef __attribute__((ext_vector_type(4))) unsigned int u32x4;

// pack two fp32 -> u32 of 2 bf16 (RNE) via v_cvt_pk_bf16_f32
__device__ __forceinline__ unsigned pk2(float lo, float hi) {
  float2 t; t.x = lo; t.y = hi;
  __hip_bfloat162 h = __float22bfloat162_rn(t);
  union { __hip_bfloat162 h; unsigned u; } c;
  c.h = h;
  return c.u;
}

// out[b][d] = sum_e sum_c xs[e][b][c]*Ws[e][c][d] + sum_e bs[e][d]
// M=262144, N=128, K=512; memory-bound.
//
// Base = R4 (145.9us best; nt was null). Single change this round: K-SLOT
// PERMUTATION for sector-efficient loads. R4's A-loads (pair of dwordx4 at
// base+hi*32, offsets 0/16) touch 2 half-used 64B sectors per row PER
// INSTRUCTION (32 sector-requests per 1KB delivered) = 2x the request rate of
// the 6.3TB/s copy pattern. MFMA is invariant under any k-bijection applied to
// both operands, so we remap lane(hi) -> k so each instruction reads ONE fully
// consumed 64B sector per row: instr#1 at row*512+kt*128+hi*16 (k=kt*32+hi*4+j),
// instr#2 at +64 (k=kt*32+16+hi*4+j). W's LDS fragment layout is permuted to
// match (same staging cost). Everything else identical to R4.
__global__ void __launch_bounds__(1024, 4)
grouped_gemm(const float* __restrict__ xs, const float* __restrict__ Ws,
             const float* __restrict__ bs, float* __restrict__ out) {
  extern __shared__ unsigned char smem[];
  unsigned short* lds_w = (unsigned short*)smem;  // 8192 entries * 16B = 128 KiB

  const int tid  = threadIdx.x;
  const int lane = tid & 63;
  const int wave = tid >> 6;       // 0..15
  const int l15  = lane & 15;
  const int hi   = lane >> 4;
  const int waveRow = blockIdx.x * 256 + wave * 16;

  // ---- bias -> registers ----
  float bias[8];
#pragma unroll
  for (int n = 0; n < 8; ++n) {
    int d = n * 16 + l15;
    bias[n] = bs[d] + bs[128 + d] + bs[256 + d] + bs[384 + d];
  }

  // ---- stage ALL W (4x128x128 fp32) -> LDS bf16, PERMUTED fragment layout ----
  // entry m: e=m>>11, g=(m>>7)&15 (g=kt*4+hi), d=m&127. 8 shorts j=0..7 hold
  // W[e][kt*32 + (j<4 ? hi*4+j : 16+hi*4+j-4)][d]  (matches the A k-permutation)
#pragma unroll
  for (int i = 0; i < 8; ++i) {
    int m = tid + i * 1024;
    int e = m >> 11;
    int g = (m >> 7) & 15;
    int d = m & 127;
    int kt = g >> 2, h2 = g & 3;
    const float* src = Ws + e * (N_C * N_C) + (kt * 32 + h2 * 4) * N_C + d;
    float v[8];
#pragma unroll
    for (int j = 0; j < 4; ++j) v[j] = src[j * N_C];           // k = kt*32+h2*4+j
#pragma unroll
    for (int j = 0; j < 4; ++j) v[4 + j] = src[(16 + j) * N_C]; // k = kt*32+16+h2*4+j
    u32x4 pk;
#pragma unroll
    for (int j = 0; j < 4; ++j) pk[j] = pk2(v[2 * j], v[2 * j + 1]);
    *reinterpret_cast<u32x4*>(&lds_w[(size_t)m * 8]) = pk;
  }

  // Drain ALL compiler-emitted vmem (bias + W gather) so loop vmcnt counts are exact.
  asm volatile("s_waitcnt vmcnt(0)" ::: "memory");
  __syncthreads();  // the only barrier

  // ---- A stream: 16 chunks (e=s>>2, kt=s&3) ----
  // lane reads 16B at row*512 + kt*128 + hi*16 and +64: both fully-consumed
  // 64B sectors (4 adjacent lanes per sector), 16 sector-requests per 1KB.
  const unsigned vb = (unsigned)(waveRow + l15) * 512u + (unsigned)hi * 16u;
  const unsigned long long xbase = (unsigned long long)xs;

  f32x4 A0[4], A1[4];  // 4-deep rotating chunk buffer (statically indexed only)

#define AISSUE(c)                                                              \
  do {                                                                         \
    unsigned o;                                                                \
    asm volatile("v_add_u32 %0, %1, %2"                                        \
                 : "=v"(o)                                                     \
                 : "n"(((c) >> 2) * 134217728u + ((c) & 3) * 128u), "v"(vb));  \
    asm volatile("global_load_dwordx4 %0, %2, %3 offset:0\n\t"                 \
                 "global_load_dwordx4 %1, %2, %3 offset:64"                    \
                 : "=&v"(A0[(c) & 3]), "=&v"(A1[(c) & 3])                      \
                 : "v"(o), "s"(xbase)                                          \
                 : "memory");                                                  \
  } while (0)

#define WAITV(n)                                          \
  do {                                                    \
    asm volatile("s_waitcnt vmcnt(" #n ")" ::: "memory"); \
    __builtin_amdgcn_sched_barrier(0);                    \
  } while (0)

  f32x4 acc[8];
#pragma unroll
  for (int n = 0; n < 8; ++n) {
    f32x4 z = {0.0f, 0.0f, 0.0f, 0.0f};
    acc[n] = z;
  }

  AISSUE(0); AISSUE(1); AISSUE(2); AISSUE(3);

  // STEP(s): wait chunk s, convert, refill slot, 8 x MFMA against LDS-resident W.
  // afrag slot j holds x[k=kt*32+khat(hi,j)]; bfrag slot j holds W[same k][d]:
  // identical k-bijection on both operands -> dot product unchanged.
#define STEP(s, w)                                                             \
  do {                                                                         \
    WAITV(w);                                                                  \
    f32x4 a0 = A0[(s) & 3];                                                    \
    f32x4 a1 = A1[(s) & 3];                                                    \
    bf16x8 afrag;                                                              \
    unsigned* au = reinterpret_cast<unsigned*>(&afrag);                        \
    au[0] = pk2(a0[0], a0[1]);                                                 \
    au[1] = pk2(a0[2], a0[3]);                                                 \
    au[2] = pk2(a1[0], a1[1]);                                                 \
    au[3] = pk2(a1[2], a1[3]);                                                 \
    if ((s) <= 11) AISSUE((s) + 4);                                            \
    const unsigned short* wb =                                                 \
        lds_w + (size_t)((((s) >> 2) * 16 + ((s) & 3) * 4 + hi) * 128 + l15) * 8; \
    _Pragma("unroll")                                                          \
    for (int n = 0; n < 8; ++n) {                                              \
      bf16x8 bfrag = *reinterpret_cast<const bf16x8*>(wb + (size_t)n * 128);   \
      acc[n] = __builtin_amdgcn_mfma_f32_16x16x32_bf16(afrag, bfrag, acc[n], 0, 0, 0); \
    }                                                                          \
  } while (0)

  STEP(0, 6);  STEP(1, 6);  STEP(2, 6);  STEP(3, 6);
  STEP(4, 6);  STEP(5, 6);  STEP(6, 6);  STEP(7, 6);
  STEP(8, 6);  STEP(9, 6);  STEP(10, 6); STEP(11, 6);
  STEP(12, 6); STEP(13, 4); STEP(14, 2); STEP(15, 0);

#undef STEP
#undef WAITV
#undef AISSUE

  // ---- epilogue: + bias, store. C/D: col=lane&15, row=(lane>>4)*4+reg ----
#pragma unroll
  for (int n = 0; n < 8; ++n) {
    int d = n * 16 + l15;
#pragma unroll
    for (int r = 0; r < 4; ++r) {
      int row = waveRow + hi * 4 + r;
      out[(size_t)row * N_C + d] = acc[n][r] + bias[n];
    }
  }
}

extern "C" void kernel_launch(void* const* d_in, const int* in_sizes, int n_in,
                              void* d_out, int out_size, void* d_ws, size_t ws_size,
                              hipStream_t stream) {
  const float* xs = (const float*)d_in[0];  // [4][262144][128] fp32
  const float* Ws = (const float*)d_in[1];  // [4][128][128] fp32
  const float* bs = (const float*)d_in[2];  // [4][128] fp32
  float* out = (float*)d_out;               // [262144][128] fp32

  const size_t smem = 131072;  // W bf16 frag layout, all 4 edge types
  hipFuncSetAttribute((const void*)grouped_gemm,
                      hipFuncAttributeMaxDynamicSharedMemorySize, (int)smem);

  dim3 grid(N_B / 256);   // 1024 blocks (256 rows each), 4 generations/CU
  dim3 block(1024);       // 16 waves -> 16 waves/CU (VGPR capped at 128)
  hipLaunchKernelGGL(grouped_gemm, grid, block, smem, stream, xs, Ws, bs, out);
}